// Round 17
// baseline (351.528 us; speedup 1.0000x reference)
//
#include <hip/hip_runtime.h>
#include <hip/hip_fp16.h>
#include <hip/hip_cooperative_groups.h>

namespace cg = cooperative_groups;

#define NN 50000
#define EE 800000
#define ELL (EE + NN)
#define NSLICE 8
#define SLICE_W (NN / NSLICE)     // 6250, exact
#define LCAP 131072               // per-slice list capacity
#define LCNT_STRIDE 16            // 64B between slice counters
#define BUCK_TILE 4096            // 256 threads x 16 edges
#define CSR_BLOCKS 256            // 1 block/CU, co-resident (cooperative)

typedef _Float16 f16x8 __attribute__((ext_vector_type(8)));
typedef float f32x4 __attribute__((ext_vector_type(4)));

__device__ __forceinline__ int edge_at(const void* ei, int is64, long long idx) {
  if (is64) return (int)((const long long*)ei)[idx];
  return ((const int*)ei)[idx];
}

__device__ __forceinline__ float leaky(float x) { return x > 0.f ? x : 0.2f * x; }

// ---------------------------------------------------------------------------
// ONE cooperative kernel = whole CSR build (was 7 launches: zero, bucket,
// count, scan1, scan2, scan3, scatter — each phase body r13/r16-validated).
// 256 blocks x 256 threads, grid.sync() between phases. Launch-gap killer.
// ---------------------------------------------------------------------------

__global__ void __launch_bounds__(256) csr_coop(const void* __restrict__ ei,
                                                unsigned* __restrict__ lists,
                                                int* __restrict__ lcnt,
                                                int* __restrict__ cnt,    // cnt,cursor,lcnt contiguous
                                                int* __restrict__ cursor,
                                                int* __restrict__ row_ptr,
                                                int* __restrict__ bsum,
                                                unsigned* __restrict__ pairs) {
  cg::grid_group grid = cg::this_grid();
  __shared__ int sflag;
  __shared__ int hist[NSLICE], sbase[NSLICE], scur[NSLICE];
  __shared__ int sh[256];
  int t = threadIdx.x;
  int b = blockIdx.x;
  int nb_grid = gridDim.x;

  // per-block dtype probe (64 L2-hit reads; replaces global flag kernel)
  if (t == 0) {
    const unsigned* wds = (const unsigned*)ei;
    unsigned acc = 0;
    for (int i = 1; i < 64; i += 2) acc |= wds[i];
    sflag = (acc == 0u) ? 1 : 0;
  }
  __syncthreads();
  int is64 = sflag;

  // ---- phase 0: zero cnt + cursor + lcnt (contiguous: 2*NN + 128 ints) ----
  for (int i = b * 256 + t; i < 2 * NN + 128; i += nb_grid * 256) cnt[i] = 0;
  grid.sync();

  // ---- phase 1: bucket (block-local two-phase append) ----
  for (long long tile = b; tile * BUCK_TILE < ELL; tile += nb_grid) {
    if (t < NSLICE) hist[t] = 0;
    __syncthreads();
    long long i0 = tile * BUCK_TILE;
    unsigned pk[16];
    int sl[16];
    #pragma unroll
    for (int j = 0; j < 16; ++j) {
      long long i = i0 + t + j * 256;
      int s = -1, d = -1;
      if (i < EE) {
        s = edge_at(ei, is64, i);
        d = edge_at(ei, is64, (long long)EE + i);
      } else if (i < ELL) {
        s = d = (int)(i - EE);
      }
      if ((unsigned)s < (unsigned)NN && (unsigned)d < (unsigned)NN) {
        sl[j] = d / SLICE_W;
        pk[j] = (unsigned)s | ((unsigned)d << 16);
        atomicAdd(&hist[sl[j]], 1);
      } else {
        sl[j] = -1;
      }
    }
    __syncthreads();
    if (t < NSLICE) {
      sbase[t] = atomicAdd(&lcnt[t * LCNT_STRIDE], hist[t]);
      scur[t] = 0;
    }
    __syncthreads();
    #pragma unroll
    for (int j = 0; j < 16; ++j) {
      if (sl[j] >= 0) {
        int pos = sbase[sl[j]] + atomicAdd(&scur[sl[j]], 1);
        if (pos < LCAP) lists[(sl[j] << 17) + pos] = pk[j];
      }
    }
    __syncthreads();
  }
  grid.sync();

  // ---- phase 2: count (slice-local) ----
  {
    int fam = b & (NSLICE - 1);
    int bf = b >> 3;
    int nf = nb_grid >> 3;
    int n = min(lcnt[fam * LCNT_STRIDE], LCAP);
    const unsigned* lp = lists + (fam << 17);
    for (int i = bf * 256 + t; i < n; i += nf * 256)
      atomicAdd(&cnt[lp[i] >> 16], 1);
  }
  grid.sync();

  // ---- phase 3: scan1 (blocks 0..48, 1024 elems each) ----
  if (b < (NN + 1023) / 1024) {
    int base = b * 1024 + t * 4;
    int v0 = 0, v1 = 0, v2 = 0, v3 = 0;
    if (base + 0 < NN) v0 = cnt[base + 0];
    if (base + 1 < NN) v1 = cnt[base + 1];
    if (base + 2 < NN) v2 = cnt[base + 2];
    if (base + 3 < NN) v3 = cnt[base + 3];
    int s = v0 + v1 + v2 + v3;
    sh[t] = s;
    __syncthreads();
    for (int off = 1; off < 256; off <<= 1) {
      int x = (t >= off) ? sh[t - off] : 0;
      __syncthreads();
      sh[t] += x;
      __syncthreads();
    }
    if (t == 255) bsum[b] = sh[255];
    int run = sh[t] - s;
    if (base + 0 < NN) row_ptr[base + 0] = run;
    run += v0;
    if (base + 1 < NN) row_ptr[base + 1] = run;
    run += v1;
    if (base + 2 < NN) row_ptr[base + 2] = run;
    run += v2;
    if (base + 3 < NN) row_ptr[base + 3] = run;
  }
  grid.sync();

  // ---- phase 4: scan2 (serial over 49 block sums) ----
  if (b == 0 && t == 0) {
    const int nbs = (NN + 1023) / 1024;
    int run = 0;
    for (int i = 0; i < nbs; ++i) { int x = bsum[i]; bsum[i] = run; run += x; }
    bsum[nbs] = run;
  }
  grid.sync();

  // ---- phase 5: scan3 (+ exact row_ptr[NN]) ----
  {
    const int nbs = (NN + 1023) / 1024;
    for (int i = b * 256 + t; i < NN; i += nb_grid * 256)
      row_ptr[i] += bsum[i >> 10];
    if (b == 0 && t == 0) row_ptr[NN] = bsum[nbs];
  }
  grid.sync();

  // ---- phase 6: scatter (slice-local) ----
  {
    int fam = b & (NSLICE - 1);
    int bf = b >> 3;
    int nf = nb_grid >> 3;
    int n = min(lcnt[fam * LCNT_STRIDE], LCAP);
    const unsigned* lp = lists + (fam << 17);
    for (int i = bf * 256 + t; i < n; i += nf * 256) {
      unsigned pk = lp[i];
      int d = pk >> 16;
      int pos = row_ptr[d] + atomicAdd(&cursor[d], 1);
      if ((unsigned)pos < (unsigned)ELL) pairs[pos] = pk;
    }
  }
}

// ---------------------------------------------------------------------------
// MFMA GEMM (r15/r16-validated): C[M, NT*16] = A[M,128] @ W[128, NT*16],
// fp16 C out, fused alpha epilogue, 2 row-tiles per block sharing staged Bt.
// ---------------------------------------------------------------------------

template <int NT, int AMODE, typename TA>
__global__ void __launch_bounds__(256) gemm_mfma(const TA* __restrict__ A,
                                                 const float* __restrict__ B,
                                                 __half* __restrict__ C,
                                                 const float* __restrict__ a_srcv,
                                                 const float* __restrict__ a_dstv,
                                                 float* __restrict__ asrc_out,
                                                 float* __restrict__ adst_out,
                                                 int M) {
  constexpr int NW = NT * 16;          // 128 or 64
  __shared__ __align__(16) __half As[64][136];
  __shared__ __align__(16) __half Bt[NW][136];     // W transposed [n][k]
  int t = threadIdx.x;

  {
    constexpr int HALF_N = NW / 2;
    constexpr int ITER = 128 * HALF_N / 256;
    #pragma unroll
    for (int i = 0; i < ITER; ++i) {
      int idx = t + i * 256;
      int k = idx / HALF_N, n0 = (idx % HALF_N) * 2;
      float2 v = *(const float2*)&B[(size_t)k * NW + n0];
      Bt[n0][k] = __float2half(v.x);
      Bt[n0 + 1][k] = __float2half(v.y);
    }
  }

  int wv = t >> 6, l = t & 63;
  int c = l & 15, rg = l >> 4;

  #pragma unroll
  for (int rt = 0; rt < 2; ++rt) {
    int row0 = (blockIdx.x * 2 + rt) * 64;
    if constexpr (sizeof(TA) == 4) {
      #pragma unroll
      for (int i = 0; i < 8; ++i) {
        int idx = t + i * 256;
        int row = idx >> 5, kq = idx & 31;
        int gr = row0 + row;
        float4 v = make_float4(0.f, 0.f, 0.f, 0.f);
        if (gr < M) v = *(const float4*)&A[(size_t)gr * 128 + kq * 4];
        __half h4[4] = {__float2half(v.x), __float2half(v.y),
                        __float2half(v.z), __float2half(v.w)};
        *(uint2*)&As[row][kq * 4] = *(uint2*)h4;
      }
    } else {
      #pragma unroll
      for (int i = 0; i < 4; ++i) {
        int idx = t + i * 256;
        int row = idx >> 4, kc = idx & 15;
        int gr = row0 + row;
        float4 raw = make_float4(0.f, 0.f, 0.f, 0.f);
        if (gr < M) raw = *(const float4*)&A[(size_t)gr * 128 + kc * 8];
        *(float4*)&As[row][kc * 8] = raw;
      }
    }
    __syncthreads();

    f32x4 acc[NT];
    #pragma unroll
    for (int ct = 0; ct < NT; ++ct) acc[ct] = (f32x4){0.f, 0.f, 0.f, 0.f};
    #pragma unroll
    for (int ks = 0; ks < 4; ++ks) {
      f16x8 af = *(const f16x8*)&As[wv * 16 + c][ks * 32 + rg * 8];
      #pragma unroll
      for (int ct = 0; ct < NT; ++ct) {
        f16x8 bf = *(const f16x8*)&Bt[ct * 16 + c][ks * 32 + rg * 8];
        acc[ct] = __builtin_amdgcn_mfma_f32_16x16x32_f16(af, bf, acc[ct], 0, 0, 0);
      }
    }

    #pragma unroll
    for (int r = 0; r < 4; ++r) {
      int grow = row0 + wv * 16 + rg * 4 + r;
      if (grow < M) {
        #pragma unroll
        for (int ct = 0; ct < NT; ++ct)
          C[(size_t)grow * NW + ct * 16 + c] = __float2half(acc[ct][r]);
      }
    }

    if constexpr (AMODE == 1) {
      float aS[8], aD[8];
      #pragma unroll
      for (int h = 0; h < 4; ++h) {
        aS[2 * h] = a_srcv[h * 32 + c];     aS[2 * h + 1] = a_srcv[h * 32 + 16 + c];
        aD[2 * h] = a_dstv[h * 32 + c];     aD[2 * h + 1] = a_dstv[h * 32 + 16 + c];
      }
      #pragma unroll
      for (int r = 0; r < 4; ++r) {
        int grow = row0 + wv * 16 + rg * 4 + r;
        #pragma unroll
        for (int h = 0; h < 4; ++h) {
          float s = acc[2 * h][r] * aS[2 * h] + acc[2 * h + 1][r] * aS[2 * h + 1];
          float d = acc[2 * h][r] * aD[2 * h] + acc[2 * h + 1][r] * aD[2 * h + 1];
          #pragma unroll
          for (int m = 1; m <= 8; m <<= 1) {
            s += __shfl_xor(s, m, 64);
            d += __shfl_xor(d, m, 64);
          }
          if (c == 0 && grow < M) {
            asrc_out[grow * 4 + h] = s;
            adst_out[grow * 4 + h] = d;
          }
        }
      }
    } else {
      float aS[NT], aD[NT];
      #pragma unroll
      for (int ct = 0; ct < NT; ++ct) {
        aS[ct] = a_srcv[ct * 16 + c];
        aD[ct] = a_dstv[ct * 16 + c];
      }
      #pragma unroll
      for (int r = 0; r < 4; ++r) {
        int grow = row0 + wv * 16 + rg * 4 + r;
        float s = 0.f, d = 0.f;
        #pragma unroll
        for (int ct = 0; ct < NT; ++ct) {
          s += acc[ct][r] * aS[ct];
          d += acc[ct][r] * aD[ct];
        }
        #pragma unroll
        for (int m = 1; m <= 8; m <<= 1) {
          s += __shfl_xor(s, m, 64);
          d += __shfl_xor(d, m, 64);
        }
        if (c == 0 && grow < M) { asrc_out[grow] = s; adst_out[grow] = d; }
      }
    }
    __syncthreads();
  }
}

// ---------------------------------------------------------------------------
// Aggregation (r16-validated configs).
// ---------------------------------------------------------------------------

// Layer 1: one wave per node, TWO edges/iter, unroll 4.
__global__ void __launch_bounds__(256) agg1_fused(
    const __half* __restrict__ h,       // [N,128] fp16
    const int* __restrict__ row_ptr,
    const unsigned* __restrict__ pairs, // (s | d<<16)
    const float* __restrict__ asrc,     // [N,4]
    const float* __restrict__ adst,     // [N,4]
    const float* __restrict__ b1,       // [128]
    __half* __restrict__ out)           // relu(agg + b1) -> [N,128] fp16
{
  int lane = threadIdx.x & 63;
  int grp = lane >> 5;
  int cl = lane & 31;
  int c0 = cl * 4;
  int myh = cl >> 3;
  int wid = (blockIdx.x * blockDim.x + threadIdx.x) >> 6;
  int nw = (gridDim.x * blockDim.x) >> 6;
  float4 bb = *(const float4*)&b1[c0];
  for (int n = wid; n < NN; n += nw) {
    int rbeg = row_ptr[n], rend = row_ptr[n + 1];
    float ad = adst[n * 4 + myh];
    float dsum = grp ? 0.f : 1e-16f;
    float a0 = 0.f, a1 = 0.f, a2 = 0.f, a3 = 0.f;
    #pragma unroll 4
    for (int e = rbeg + grp; e < rend; e += 2) {
      int s = pairs[e] & 0xFFFF;
      float wgt = __expf(leaky(asrc[s * 4 + myh] + ad));
      float2 raw = *(const float2*)&h[(size_t)s * 128 + c0];
      float2 f01 = __half22float2(__builtin_bit_cast(__half2, raw.x));
      float2 f23 = __half22float2(__builtin_bit_cast(__half2, raw.y));
      dsum += wgt;
      a0 += wgt * f01.x; a1 += wgt * f01.y;
      a2 += wgt * f23.x; a3 += wgt * f23.y;
    }
    dsum += __shfl_xor(dsum, 32, 64);
    a0 += __shfl_xor(a0, 32, 64);
    a1 += __shfl_xor(a1, 32, 64);
    a2 += __shfl_xor(a2, 32, 64);
    a3 += __shfl_xor(a3, 32, 64);
    if (lane < 32) {
      float inv = 1.f / dsum;
      __half ot[4];
      ot[0] = __float2half(fmaxf(a0 * inv + bb.x, 0.f));
      ot[1] = __float2half(fmaxf(a1 * inv + bb.y, 0.f));
      ot[2] = __float2half(fmaxf(a2 * inv + bb.z, 0.f));
      ot[3] = __float2half(fmaxf(a3 * inv + bb.w, 0.f));
      *(uint2*)&out[(size_t)n * 128 + c0] = *(uint2*)ot;  // fused ReLU, fp16
    }
  }
}

// Layer 2: one wave per node, EIGHT edges/iter (8-lane groups, 16B/lane).
__global__ void __launch_bounds__(256) agg2_kernel(
    const __half* __restrict__ h,       // [N,64] fp16
    const int* __restrict__ row_ptr,
    const unsigned* __restrict__ pairs,
    const float* __restrict__ asrc,     // [N]
    const float* __restrict__ adst,     // [N]
    const float* __restrict__ b2,       // [64]
    float* __restrict__ out)            // [N,64] fp32
{
  int lane = threadIdx.x & 63;
  int grp = lane >> 3;                  // edge residue (0..7)
  int cl = lane & 7;
  int c0 = cl * 8;                      // 8 owned channels
  int wid = (blockIdx.x * blockDim.x + threadIdx.x) >> 6;
  int nw = (gridDim.x * blockDim.x) >> 6;
  float4 bbA = *(const float4*)&b2[c0];
  float4 bbB = *(const float4*)&b2[c0 + 4];
  for (int n = wid; n < NN; n += nw) {
    int rbeg = row_ptr[n], rend = row_ptr[n + 1];
    float ad = adst[n];
    float dsum = (grp == 0) ? 1e-16f : 0.f;
    float a0 = 0.f, a1 = 0.f, a2 = 0.f, a3 = 0.f;
    float a4 = 0.f, a5 = 0.f, a6 = 0.f, a7 = 0.f;
    #pragma unroll 2
    for (int e = rbeg + grp; e < rend; e += 8) {
      int s = pairs[e] & 0xFFFF;
      float wgt = __expf(leaky(asrc[s] + ad));
      float4 raw = *(const float4*)&h[(size_t)s * 64 + c0];  // 16B = 8 halves
      float2 f01 = __half22float2(__builtin_bit_cast(__half2, raw.x));
      float2 f23 = __half22float2(__builtin_bit_cast(__half2, raw.y));
      float2 f45 = __half22float2(__builtin_bit_cast(__half2, raw.z));
      float2 f67 = __half22float2(__builtin_bit_cast(__half2, raw.w));
      dsum += wgt;
      a0 += wgt * f01.x; a1 += wgt * f01.y;
      a2 += wgt * f23.x; a3 += wgt * f23.y;
      a4 += wgt * f45.x; a5 += wgt * f45.y;
      a6 += wgt * f67.x; a7 += wgt * f67.y;
    }
    #pragma unroll
    for (int m = 8; m <= 32; m <<= 1) {
      dsum += __shfl_xor(dsum, m, 64);
      a0 += __shfl_xor(a0, m, 64);
      a1 += __shfl_xor(a1, m, 64);
      a2 += __shfl_xor(a2, m, 64);
      a3 += __shfl_xor(a3, m, 64);
      a4 += __shfl_xor(a4, m, 64);
      a5 += __shfl_xor(a5, m, 64);
      a6 += __shfl_xor(a6, m, 64);
      a7 += __shfl_xor(a7, m, 64);
    }
    if (lane < 8) {
      float inv = 1.f / dsum;
      float4 oA = make_float4(a0 * inv + bbA.x, a1 * inv + bbA.y,
                              a2 * inv + bbA.z, a3 * inv + bbA.w);
      float4 oB = make_float4(a4 * inv + bbB.x, a5 * inv + bbB.y,
                              a6 * inv + bbB.z, a7 * inv + bbB.w);
      *(float4*)&out[(size_t)n * 64 + c0] = oA;
      *(float4*)&out[(size_t)n * 64 + c0 + 4] = oB;
    }
  }
}

// ---------------------------------------------------------------------------

extern "C" void kernel_launch(void* const* d_in, const int* in_sizes, int n_in,
                              void* d_out, int out_size, void* d_ws, size_t ws_size,
                              hipStream_t stream) {
  const float* x   = (const float*)d_in[0];
  const void*  ei  = d_in[1];               // int32 or int64, probed on device
  const float* W1  = (const float*)d_in[2];
  const float* as1 = (const float*)d_in[3];
  const float* ad1 = (const float*)d_in[4];
  const float* b1  = (const float*)d_in[5];
  const float* W2  = (const float*)d_in[6];
  const float* as2 = (const float*)d_in[7];
  const float* ad2 = (const float*)d_in[8];
  const float* b2  = (const float*)d_in[9];
  float* out = (float*)d_out;

  char* w = (char*)d_ws;
  __half* h1h  = (__half*)w; w += (size_t)NN * 128 * 2;  // layer-1 features fp16
  __half* hb2h = h1h;                                    // alias: dead after agg1
  __half* h2   = (__half*)w; w += (size_t)NN * 128 * 2;  // relu(GAT1 out) fp16
  float* asrc1 = (float*)w; w += (size_t)NN * 4 * 4;
  float* adst1 = (float*)w; w += (size_t)NN * 4 * 4;
  float* asrc2 = (float*)w; w += (size_t)NN * 4;
  float* adst2 = (float*)w; w += (size_t)NN * 4;
  int* cnt     = (int*)w;   w += (size_t)NN * 4;         // cnt+cursor+lcnt adjacent
  int* cursor  = (int*)w;   w += (size_t)NN * 4;
  int* lcnt    = (int*)w;   w += 512;                    // 8 counters, 64B apart
  int* row_ptr = (int*)w;   w += (size_t)(NN + 1) * 4;
  int* bsum    = (int*)w;   w += 256;
  unsigned* lists = (unsigned*)w; w += (size_t)NSLICE * LCAP * 4;  // 4.2MB
  unsigned* pairs = (unsigned*)w; w += (size_t)ELL * 4;            // (s|d<<16)

  const int MB128 = (NN + 127) / 128;  // 391 (each block: 2 x 64-row tiles)

  // ONE cooperative kernel: zero + dtype-probe + bucket + count + scan + scatter
  {
    void* args[] = {(void*)&ei, (void*)&lists, (void*)&lcnt, (void*)&cnt,
                    (void*)&cursor, (void*)&row_ptr, (void*)&bsum, (void*)&pairs};
    hipLaunchCooperativeKernel((void*)csr_coop, dim3(CSR_BLOCKS), dim3(256),
                               args, 0, stream);
  }

  // Layer 1 GEMM (MFMA): h1h = x @ W1, alphas fused
  gemm_mfma<8, 1, float><<<MB128, 256, 0, stream>>>(
      x, W1, h1h, as1, ad1, asrc1, adst1, NN);

  agg1_fused<<<4096, 256, 0, stream>>>(h1h, row_ptr, pairs, asrc1, adst1, b1, h2);

  // Layer 2 GEMM (MFMA, fp16 A): hb2h = h2 @ W2, alphas fused
  gemm_mfma<4, 2, __half><<<MB128, 256, 0, stream>>>(
      h2, W2, hb2h, as2, ad2, asrc2, adst2, NN);
  agg2_kernel<<<4096, 256, 0, stream>>>(hb2h, row_ptr, pairs, asrc2, adst2, b2, out);
}

// Round 18
// 188.707 us; speedup vs baseline: 1.8628x; 1.8628x over previous
//
#include <hip/hip_runtime.h>
#include <hip/hip_fp16.h>

#define NN 50000
#define EE 800000
#define ELL (EE + NN)
#define NSLICE 8
#define SLICE_W (NN / NSLICE)     // 6250, exact
#define LCAP 131072               // per-slice list capacity
#define LCNT_STRIDE 16            // 64B between slice counters
#define BUCK_TILE 4096            // 256 threads x 16 edges

typedef _Float16 f16x8 __attribute__((ext_vector_type(8)));
typedef float f32x4 __attribute__((ext_vector_type(4)));

__device__ __forceinline__ int edge_at(const void* ei, int is64, long long idx) {
  if (is64) return (int)((const long long*)ei)[idx];
  return ((const int*)ei)[idx];
}

__device__ __forceinline__ float leaky(float x) { return x > 0.f ? x : 0.2f * x; }

// ---------------------------------------------------------------------------
// zero + edge-dtype probe fused. int64 LE with values < 2^31 => odd words 0.
// ---------------------------------------------------------------------------

__global__ void __launch_bounds__(256) zero_detect_kernel(int* __restrict__ p, int n,
                                                          const unsigned* __restrict__ ei_words,
                                                          int* __restrict__ flag) {
  if (blockIdx.x == 0 && threadIdx.x == 0) {
    unsigned acc = 0;
    for (int i = 1; i < 64; i += 2) acc |= ei_words[i];
    *flag = (acc == 0u) ? 1 : 0;
  }
  int stride = gridDim.x * blockDim.x;
  for (int i = blockIdx.x * blockDim.x + threadIdx.x; i < n; i += stride) p[i] = 0;
}

// ---------------------------------------------------------------------------
// Bucket pass + degree count fused (bucket body r13-validated; count is an
// order-free atomicAdd on the in-register d — deletes the count kernel).
// ---------------------------------------------------------------------------

__global__ void __launch_bounds__(256) bucket_kernel(const void* __restrict__ ei,
                                                     const int* __restrict__ flag,
                                                     unsigned* __restrict__ lists,
                                                     int* __restrict__ lcnt,
                                                     int* __restrict__ cnt) {
  __shared__ int hist[NSLICE];
  __shared__ int base[NSLICE];
  __shared__ int cur[NSLICE];
  int is64 = *flag;
  int t = threadIdx.x;
  if (t < NSLICE) hist[t] = 0;
  __syncthreads();
  long long i0 = (long long)blockIdx.x * BUCK_TILE;
  unsigned pk[16];
  int sl[16];
  #pragma unroll
  for (int j = 0; j < 16; ++j) {
    long long i = i0 + t + j * 256;
    int s = -1, d = -1;
    if (i < EE) {
      s = edge_at(ei, is64, i);
      d = edge_at(ei, is64, (long long)EE + i);
    } else if (i < ELL) {
      s = d = (int)(i - EE);
    }
    if ((unsigned)s < (unsigned)NN && (unsigned)d < (unsigned)NN) {
      sl[j] = d / SLICE_W;
      pk[j] = (unsigned)s | ((unsigned)d << 16);
      atomicAdd(&hist[sl[j]], 1);
      atomicAdd(&cnt[d], 1);               // fused degree count (order-free)
    } else {
      sl[j] = -1;
    }
  }
  __syncthreads();
  if (t < NSLICE) {
    base[t] = atomicAdd(&lcnt[t * LCNT_STRIDE], hist[t]);
    cur[t] = 0;
  }
  __syncthreads();
  #pragma unroll
  for (int j = 0; j < 16; ++j) {
    if (sl[j] >= 0) {
      int pos = base[sl[j]] + atomicAdd(&cur[sl[j]], 1);
      if (pos < LCAP) lists[(sl[j] << 17) + pos] = pk[j];
    }
  }
}

// ---------------------------------------------------------------------------
// Scans (r5-validated) + slice-local scatter (r13-validated).
// ---------------------------------------------------------------------------

__global__ void __launch_bounds__(256) scan1_kernel(const int* __restrict__ cnt,
                                                    int* __restrict__ excl,
                                                    int* __restrict__ bsum) {
  __shared__ int sh[256];
  int t = threadIdx.x;
  int base = blockIdx.x * 1024 + t * 4;
  int v0 = 0, v1 = 0, v2 = 0, v3 = 0;
  if (base + 0 < NN) v0 = cnt[base + 0];
  if (base + 1 < NN) v1 = cnt[base + 1];
  if (base + 2 < NN) v2 = cnt[base + 2];
  if (base + 3 < NN) v3 = cnt[base + 3];
  int s = v0 + v1 + v2 + v3;
  sh[t] = s;
  __syncthreads();
  for (int off = 1; off < 256; off <<= 1) {
    int x = (t >= off) ? sh[t - off] : 0;
    __syncthreads();
    sh[t] += x;
    __syncthreads();
  }
  if (t == 255) bsum[blockIdx.x] = sh[255];
  int run = sh[t] - s;
  if (base + 0 < NN) excl[base + 0] = run;
  run += v0;
  if (base + 1 < NN) excl[base + 1] = run;
  run += v1;
  if (base + 2 < NN) excl[base + 2] = run;
  run += v2;
  if (base + 3 < NN) excl[base + 3] = run;
}

__global__ void scan2_kernel(int* __restrict__ bsum, int nb) {
  if (threadIdx.x == 0 && blockIdx.x == 0) {
    int run = 0;
    for (int i = 0; i < nb; ++i) { int x = bsum[i]; bsum[i] = run; run += x; }
    bsum[nb] = run;
  }
}

__global__ void __launch_bounds__(256) scan3_kernel(int* __restrict__ row_ptr,
                                                    const int* __restrict__ bsum,
                                                    int nb) {
  int i = blockIdx.x * blockDim.x + threadIdx.x;
  if (i < NN) row_ptr[i] += bsum[i >> 10];
  if (i == 0) row_ptr[NN] = bsum[nb];
}

__global__ void __launch_bounds__(256) scatter_kernel(const unsigned* __restrict__ lists,
                                                      const int* __restrict__ lcnt,
                                                      const int* __restrict__ row_ptr,
                                                      int* __restrict__ cursor,
                                                      unsigned* __restrict__ pairs) {
  int fam = blockIdx.x & (NSLICE - 1);
  int bf = blockIdx.x >> 3;
  int nf = gridDim.x >> 3;
  int n = min(lcnt[fam * LCNT_STRIDE], LCAP);
  const unsigned* lp = lists + (fam << 17);
  for (int i = bf * blockDim.x + threadIdx.x; i < n; i += nf * blockDim.x) {
    unsigned pk = lp[i];
    int d = pk >> 16;
    int pos = row_ptr[d] + atomicAdd(&cursor[d], 1);
    if ((unsigned)pos < (unsigned)ELL) pairs[pos] = pk;
  }
}

// ---------------------------------------------------------------------------
// MFMA GEMM (r15/r16-validated): C[M, NT*16] = A[M,128] @ W[128, NT*16],
// fp16 C out, fused alpha epilogue, 2 row-tiles per block sharing staged Bt.
// v_mfma_f32_16x16x32_f16: A/B lane l -> row/col l&15, k0=(l>>4)*8;
// C/D: col=lane&15, row=(lane>>4)*4+reg  [m89-verified].
// ---------------------------------------------------------------------------

template <int NT, int AMODE, typename TA>
__global__ void __launch_bounds__(256) gemm_mfma(const TA* __restrict__ A,
                                                 const float* __restrict__ B,
                                                 __half* __restrict__ C,
                                                 const float* __restrict__ a_srcv,
                                                 const float* __restrict__ a_dstv,
                                                 float* __restrict__ asrc_out,
                                                 float* __restrict__ adst_out,
                                                 int M) {
  constexpr int NW = NT * 16;          // 128 or 64
  __shared__ __align__(16) __half As[64][136];
  __shared__ __align__(16) __half Bt[NW][136];     // W transposed [n][k]
  int t = threadIdx.x;

  {
    constexpr int HALF_N = NW / 2;
    constexpr int ITER = 128 * HALF_N / 256;
    #pragma unroll
    for (int i = 0; i < ITER; ++i) {
      int idx = t + i * 256;
      int k = idx / HALF_N, n0 = (idx % HALF_N) * 2;
      float2 v = *(const float2*)&B[(size_t)k * NW + n0];
      Bt[n0][k] = __float2half(v.x);
      Bt[n0 + 1][k] = __float2half(v.y);
    }
  }

  int wv = t >> 6, l = t & 63;
  int c = l & 15, rg = l >> 4;

  #pragma unroll
  for (int rt = 0; rt < 2; ++rt) {
    int row0 = (blockIdx.x * 2 + rt) * 64;
    if constexpr (sizeof(TA) == 4) {
      #pragma unroll
      for (int i = 0; i < 8; ++i) {
        int idx = t + i * 256;
        int row = idx >> 5, kq = idx & 31;
        int gr = row0 + row;
        float4 v = make_float4(0.f, 0.f, 0.f, 0.f);
        if (gr < M) v = *(const float4*)&A[(size_t)gr * 128 + kq * 4];
        __half h4[4] = {__float2half(v.x), __float2half(v.y),
                        __float2half(v.z), __float2half(v.w)};
        *(uint2*)&As[row][kq * 4] = *(uint2*)h4;
      }
    } else {
      #pragma unroll
      for (int i = 0; i < 4; ++i) {
        int idx = t + i * 256;
        int row = idx >> 4, kc = idx & 15;
        int gr = row0 + row;
        float4 raw = make_float4(0.f, 0.f, 0.f, 0.f);
        if (gr < M) raw = *(const float4*)&A[(size_t)gr * 128 + kc * 8];
        *(float4*)&As[row][kc * 8] = raw;
      }
    }
    __syncthreads();

    f32x4 acc[NT];
    #pragma unroll
    for (int ct = 0; ct < NT; ++ct) acc[ct] = (f32x4){0.f, 0.f, 0.f, 0.f};
    #pragma unroll
    for (int ks = 0; ks < 4; ++ks) {
      f16x8 af = *(const f16x8*)&As[wv * 16 + c][ks * 32 + rg * 8];
      #pragma unroll
      for (int ct = 0; ct < NT; ++ct) {
        f16x8 bf = *(const f16x8*)&Bt[ct * 16 + c][ks * 32 + rg * 8];
        acc[ct] = __builtin_amdgcn_mfma_f32_16x16x32_f16(af, bf, acc[ct], 0, 0, 0);
      }
    }

    #pragma unroll
    for (int r = 0; r < 4; ++r) {
      int grow = row0 + wv * 16 + rg * 4 + r;
      if (grow < M) {
        #pragma unroll
        for (int ct = 0; ct < NT; ++ct)
          C[(size_t)grow * NW + ct * 16 + c] = __float2half(acc[ct][r]);
      }
    }

    if constexpr (AMODE == 1) {
      float aS[8], aD[8];
      #pragma unroll
      for (int h = 0; h < 4; ++h) {
        aS[2 * h] = a_srcv[h * 32 + c];     aS[2 * h + 1] = a_srcv[h * 32 + 16 + c];
        aD[2 * h] = a_dstv[h * 32 + c];     aD[2 * h + 1] = a_dstv[h * 32 + 16 + c];
      }
      #pragma unroll
      for (int r = 0; r < 4; ++r) {
        int grow = row0 + wv * 16 + rg * 4 + r;
        #pragma unroll
        for (int h = 0; h < 4; ++h) {
          float s = acc[2 * h][r] * aS[2 * h] + acc[2 * h + 1][r] * aS[2 * h + 1];
          float d = acc[2 * h][r] * aD[2 * h] + acc[2 * h + 1][r] * aD[2 * h + 1];
          #pragma unroll
          for (int m = 1; m <= 8; m <<= 1) {
            s += __shfl_xor(s, m, 64);
            d += __shfl_xor(d, m, 64);
          }
          if (c == 0 && grow < M) {
            asrc_out[grow * 4 + h] = s;
            adst_out[grow * 4 + h] = d;
          }
        }
      }
    } else {
      float aS[NT], aD[NT];
      #pragma unroll
      for (int ct = 0; ct < NT; ++ct) {
        aS[ct] = a_srcv[ct * 16 + c];
        aD[ct] = a_dstv[ct * 16 + c];
      }
      #pragma unroll
      for (int r = 0; r < 4; ++r) {
        int grow = row0 + wv * 16 + rg * 4 + r;
        float s = 0.f, d = 0.f;
        #pragma unroll
        for (int ct = 0; ct < NT; ++ct) {
          s += acc[ct][r] * aS[ct];
          d += acc[ct][r] * aD[ct];
        }
        #pragma unroll
        for (int m = 1; m <= 8; m <<= 1) {
          s += __shfl_xor(s, m, 64);
          d += __shfl_xor(d, m, 64);
        }
        if (c == 0 && grow < M) { asrc_out[grow] = s; adst_out[grow] = d; }
      }
    }
    __syncthreads();
  }
}

// ---------------------------------------------------------------------------
// Aggregation (r16-validated configs).
// ---------------------------------------------------------------------------

// Layer 1: one wave per node, TWO edges/iter, unroll 4.
__global__ void __launch_bounds__(256) agg1_fused(
    const __half* __restrict__ h,       // [N,128] fp16
    const int* __restrict__ row_ptr,
    const unsigned* __restrict__ pairs, // (s | d<<16)
    const float* __restrict__ asrc,     // [N,4]
    const float* __restrict__ adst,     // [N,4]
    const float* __restrict__ b1,       // [128]
    __half* __restrict__ out)           // relu(agg + b1) -> [N,128] fp16
{
  int lane = threadIdx.x & 63;
  int grp = lane >> 5;
  int cl = lane & 31;
  int c0 = cl * 4;
  int myh = cl >> 3;
  int wid = (blockIdx.x * blockDim.x + threadIdx.x) >> 6;
  int nw = (gridDim.x * blockDim.x) >> 6;
  float4 bb = *(const float4*)&b1[c0];
  for (int n = wid; n < NN; n += nw) {
    int rbeg = row_ptr[n], rend = row_ptr[n + 1];
    float ad = adst[n * 4 + myh];
    float dsum = grp ? 0.f : 1e-16f;
    float a0 = 0.f, a1 = 0.f, a2 = 0.f, a3 = 0.f;
    #pragma unroll 4
    for (int e = rbeg + grp; e < rend; e += 2) {
      int s = pairs[e] & 0xFFFF;
      float wgt = __expf(leaky(asrc[s * 4 + myh] + ad));
      float2 raw = *(const float2*)&h[(size_t)s * 128 + c0];
      float2 f01 = __half22float2(__builtin_bit_cast(__half2, raw.x));
      float2 f23 = __half22float2(__builtin_bit_cast(__half2, raw.y));
      dsum += wgt;
      a0 += wgt * f01.x; a1 += wgt * f01.y;
      a2 += wgt * f23.x; a3 += wgt * f23.y;
    }
    dsum += __shfl_xor(dsum, 32, 64);
    a0 += __shfl_xor(a0, 32, 64);
    a1 += __shfl_xor(a1, 32, 64);
    a2 += __shfl_xor(a2, 32, 64);
    a3 += __shfl_xor(a3, 32, 64);
    if (lane < 32) {
      float inv = 1.f / dsum;
      __half ot[4];
      ot[0] = __float2half(fmaxf(a0 * inv + bb.x, 0.f));
      ot[1] = __float2half(fmaxf(a1 * inv + bb.y, 0.f));
      ot[2] = __float2half(fmaxf(a2 * inv + bb.z, 0.f));
      ot[3] = __float2half(fmaxf(a3 * inv + bb.w, 0.f));
      *(uint2*)&out[(size_t)n * 128 + c0] = *(uint2*)ot;  // fused ReLU, fp16
    }
  }
}

// Layer 2: one wave per node, EIGHT edges/iter (8-lane groups, 16B/lane).
__global__ void __launch_bounds__(256) agg2_kernel(
    const __half* __restrict__ h,       // [N,64] fp16
    const int* __restrict__ row_ptr,
    const unsigned* __restrict__ pairs,
    const float* __restrict__ asrc,     // [N]
    const float* __restrict__ adst,     // [N]
    const float* __restrict__ b2,       // [64]
    float* __restrict__ out)            // [N,64] fp32
{
  int lane = threadIdx.x & 63;
  int grp = lane >> 3;                  // edge residue (0..7)
  int cl = lane & 7;
  int c0 = cl * 8;                      // 8 owned channels
  int wid = (blockIdx.x * blockDim.x + threadIdx.x) >> 6;
  int nw = (gridDim.x * blockDim.x) >> 6;
  float4 bbA = *(const float4*)&b2[c0];
  float4 bbB = *(const float4*)&b2[c0 + 4];
  for (int n = wid; n < NN; n += nw) {
    int rbeg = row_ptr[n], rend = row_ptr[n + 1];
    float ad = adst[n];
    float dsum = (grp == 0) ? 1e-16f : 0.f;
    float a0 = 0.f, a1 = 0.f, a2 = 0.f, a3 = 0.f;
    float a4 = 0.f, a5 = 0.f, a6 = 0.f, a7 = 0.f;
    #pragma unroll 2
    for (int e = rbeg + grp; e < rend; e += 8) {
      int s = pairs[e] & 0xFFFF;
      float wgt = __expf(leaky(asrc[s] + ad));
      float4 raw = *(const float4*)&h[(size_t)s * 64 + c0];  // 16B = 8 halves
      float2 f01 = __half22float2(__builtin_bit_cast(__half2, raw.x));
      float2 f23 = __half22float2(__builtin_bit_cast(__half2, raw.y));
      float2 f45 = __half22float2(__builtin_bit_cast(__half2, raw.z));
      float2 f67 = __half22float2(__builtin_bit_cast(__half2, raw.w));
      dsum += wgt;
      a0 += wgt * f01.x; a1 += wgt * f01.y;
      a2 += wgt * f23.x; a3 += wgt * f23.y;
      a4 += wgt * f45.x; a5 += wgt * f45.y;
      a6 += wgt * f67.x; a7 += wgt * f67.y;
    }
    #pragma unroll
    for (int m = 8; m <= 32; m <<= 1) {
      dsum += __shfl_xor(dsum, m, 64);
      a0 += __shfl_xor(a0, m, 64);
      a1 += __shfl_xor(a1, m, 64);
      a2 += __shfl_xor(a2, m, 64);
      a3 += __shfl_xor(a3, m, 64);
      a4 += __shfl_xor(a4, m, 64);
      a5 += __shfl_xor(a5, m, 64);
      a6 += __shfl_xor(a6, m, 64);
      a7 += __shfl_xor(a7, m, 64);
    }
    if (lane < 8) {
      float inv = 1.f / dsum;
      float4 oA = make_float4(a0 * inv + bbA.x, a1 * inv + bbA.y,
                              a2 * inv + bbA.z, a3 * inv + bbA.w);
      float4 oB = make_float4(a4 * inv + bbB.x, a5 * inv + bbB.y,
                              a6 * inv + bbB.z, a7 * inv + bbB.w);
      *(float4*)&out[(size_t)n * 64 + c0] = oA;
      *(float4*)&out[(size_t)n * 64 + c0 + 4] = oB;
    }
  }
}

// ---------------------------------------------------------------------------

extern "C" void kernel_launch(void* const* d_in, const int* in_sizes, int n_in,
                              void* d_out, int out_size, void* d_ws, size_t ws_size,
                              hipStream_t stream) {
  const float* x   = (const float*)d_in[0];
  const void*  ei  = d_in[1];               // int32 or int64, probed on device
  const float* W1  = (const float*)d_in[2];
  const float* as1 = (const float*)d_in[3];
  const float* ad1 = (const float*)d_in[4];
  const float* b1  = (const float*)d_in[5];
  const float* W2  = (const float*)d_in[6];
  const float* as2 = (const float*)d_in[7];
  const float* ad2 = (const float*)d_in[8];
  const float* b2  = (const float*)d_in[9];
  float* out = (float*)d_out;

  char* w = (char*)d_ws;
  __half* h1h  = (__half*)w; w += (size_t)NN * 128 * 2;  // layer-1 features fp16
  __half* hb2h = h1h;                                    // alias: dead after agg1
  __half* h2   = (__half*)w; w += (size_t)NN * 128 * 2;  // relu(GAT1 out) fp16
  float* asrc1 = (float*)w; w += (size_t)NN * 4 * 4;
  float* adst1 = (float*)w; w += (size_t)NN * 4 * 4;
  float* asrc2 = (float*)w; w += (size_t)NN * 4;
  float* adst2 = (float*)w; w += (size_t)NN * 4;
  int* cnt     = (int*)w;   w += (size_t)NN * 4;         // cnt+cursor+lcnt adjacent
  int* cursor  = (int*)w;   w += (size_t)NN * 4;
  int* lcnt    = (int*)w;   w += 512;                    // 8 counters, 64B apart
  int* row_ptr = (int*)w;   w += (size_t)(NN + 1) * 4;
  int* bsum    = (int*)w;   w += 256;
  int* is64    = (int*)w;   w += 256;
  unsigned* lists = (unsigned*)w; w += (size_t)NSLICE * LCAP * 4;  // 4.2MB
  unsigned* pairs = (unsigned*)w; w += (size_t)ELL * 4;            // (s|d<<16)

  const int NB = (NN + 1023) / 1024;   // 49
  const int MB128 = (NN + 127) / 128;  // 391 (each block: 2 x 64-row tiles)
  const int BUCK_BLOCKS = (ELL + BUCK_TILE - 1) / BUCK_TILE;  // 208

  zero_detect_kernel<<<256, 256, 0, stream>>>(cnt, 2 * NN + 128, (const unsigned*)ei, is64);
  bucket_kernel<<<BUCK_BLOCKS, 256, 0, stream>>>(ei, is64, lists, lcnt, cnt);  // +count fused
  scan1_kernel<<<NB, 256, 0, stream>>>(cnt, row_ptr, bsum);
  scan2_kernel<<<1, 64, 0, stream>>>(bsum, NB);
  scan3_kernel<<<(NN + 255) / 256, 256, 0, stream>>>(row_ptr, bsum, NB);

  // Layer 1 GEMM (MFMA): h1h = x @ W1, alphas fused
  gemm_mfma<8, 1, float><<<MB128, 256, 0, stream>>>(
      x, W1, h1h, as1, ad1, asrc1, adst1, NN);

  scatter_kernel<<<2048, 256, 0, stream>>>(lists, lcnt, row_ptr, cursor, pairs);

  agg1_fused<<<4096, 256, 0, stream>>>(h1h, row_ptr, pairs, asrc1, adst1, b1, h2);

  // Layer 2 GEMM (MFMA, fp16 A): hb2h = h2 @ W2, alphas fused
  gemm_mfma<4, 2, __half><<<MB128, 256, 0, stream>>>(
      h2, W2, hb2h, as2, ad2, asrc2, adst2, NN);
  agg2_kernel<<<4096, 256, 0, stream>>>(hb2h, row_ptr, pairs, asrc2, adst2, b2, out);
}